// Round 6
// baseline (475.431 us; speedup 1.0000x reference)
//
#include <hip/hip_runtime.h>

// NODE ensemble forward — ROUND 5 = DIAGNOSTIC BUILD.
// Purpose: R4's fused kernel runs ~28us vs a ~10us first-principles model and
// its counters are hidden below the harness's ~40us fillBuffer dispatches.
// This build rep-loops the phases x16 so each shows up in the rocprof top-5
// with full counters, and splits gemm-phase vs fold-phase attribution:
//   node_diag_gemm (B): 16x {breg load (pk copy blockIdx&7) + x-stream tiles
//                       + MFMA + sigmoid->pr LDS} + checksum -> ws
//   node_diag_full (A): same + per-rep fold + out (correct output, idempotent)
//   gemm phase ~= B/16 ; fold phase ~= (A-B)/16 ; pk is x8-replicated to kill
//   the all-CUs-convoy-on-one-L3-range startup effect (copy per XCD).
//
// B=16384, D=512, T=64, DEPTH=6, NCOL=384.

#define DD     512
#define NCOL   384
#define NDEPTH 6
#define REPS   16
#define PKELT  (NCOL * DD)     // elements per pk copy (196608)

typedef __bf16 bf16_t;
typedef __bf16 bf16x8 __attribute__((ext_vector_type(8)));
typedef float  f32x4  __attribute__((ext_vector_type(4)));

static __device__ __forceinline__ float b2f(unsigned int u16) {
  unsigned int t = u16 << 16;
  float f;
  __builtin_memcpy(&f, &t, 4);
  return f;
}

// pk[c][((cf*16 + ksg)*64 + lane)*8 + j] = fsel[cf*16+(lane&15)][ksg*32+(lane>>4)*8+j]
// replicated into 8 copies (one per XCD's L2)
__global__ __launch_bounds__(256) void node_pack(const float* __restrict__ fsel,
                                                 bf16_t* __restrict__ pk)
{
  int tid  = blockIdx.x * 256 + threadIdx.x;   // 0..24575
  int lane = tid & 63;
  int ksg  = (tid >> 6) & 15;
  int cf   = tid >> 10;                        // 0..23
  int col  = cf * 16 + (lane & 15);
  int k    = ksg * 32 + (lane >> 4) * 8;
  float4 f0 = *reinterpret_cast<const float4*>(fsel + (size_t)col * DD + k);
  float4 f1 = *reinterpret_cast<const float4*>(fsel + (size_t)col * DD + k + 4);
  bf16x8 v;
  v[0] = (bf16_t)f0.x; v[1] = (bf16_t)f0.y; v[2] = (bf16_t)f0.z; v[3] = (bf16_t)f0.w;
  v[4] = (bf16_t)f1.x; v[5] = (bf16_t)f1.y; v[6] = (bf16_t)f1.z; v[7] = (bf16_t)f1.w;
  #pragma unroll
  for (int c = 0; c < 8; ++c)
    *reinterpret_cast<bf16x8*>(pk + (size_t)c * PKELT + (size_t)tid * 8) = v;
}

// ---- shared body macros (identical structure to R4's node_fused) ----
#define DIAG_PROLOGUE()                                                         \
  __shared__ bf16_t xf[8192];          /* 16 KiB: x tile, MFMA frag layout */   \
  __shared__ bf16_t pr[64 * NCOL];     /* 48 KiB: sigmoid probs, 64 rows  */    \
  const int tid  = threadIdx.x;                                                 \
  const int lane = tid & 63;                                                    \
  const int wv   = tid >> 6;                                                    \
  const int rowblk = blockIdx.x * 64;                                           \
  const int srow = lane & 15;                                                   \
  const int skg  = lane >> 4;                                                   \
  const bf16_t* pkc = pk + (size_t)(blockIdx.x & 7) * PKELT;                    \
  float th[3];                                                                  \
  _Pragma("unroll")                                                             \
  for (int f = 0; f < 3; ++f) th[f] = thr[wv * 48 + f * 16 + (lane & 15)];

#define ISSUE_LOADS(t)                                                          \
  do {                                                                          \
    const float* base_ = x + (size_t)(rowblk + (t) * 16 + srow) * DD + skg*8;   \
    st[0] = *reinterpret_cast<const float4*>(base_ + wv * 32);                  \
    st[1] = *reinterpret_cast<const float4*>(base_ + wv * 32 + 4);              \
    st[2] = *reinterpret_cast<const float4*>(base_ + (wv + 8) * 32);            \
    st[3] = *reinterpret_cast<const float4*>(base_ + (wv + 8) * 32 + 4);        \
  } while (0)

#define WRITE_LDS()                                                             \
  do {                                                                          \
    bf16x8 v0_, v1_;                                                            \
    v0_[0]=(bf16_t)st[0].x; v0_[1]=(bf16_t)st[0].y;                             \
    v0_[2]=(bf16_t)st[0].z; v0_[3]=(bf16_t)st[0].w;                             \
    v0_[4]=(bf16_t)st[1].x; v0_[5]=(bf16_t)st[1].y;                             \
    v0_[6]=(bf16_t)st[1].z; v0_[7]=(bf16_t)st[1].w;                             \
    v1_[0]=(bf16_t)st[2].x; v1_[1]=(bf16_t)st[2].y;                             \
    v1_[2]=(bf16_t)st[2].z; v1_[3]=(bf16_t)st[2].w;                             \
    v1_[4]=(bf16_t)st[3].x; v1_[5]=(bf16_t)st[3].y;                             \
    v1_[6]=(bf16_t)st[3].z; v1_[7]=(bf16_t)st[3].w;                             \
    *reinterpret_cast<bf16x8*>(&xf[(wv * 64 + lane) * 8])       = v0_;          \
    *reinterpret_cast<bf16x8*>(&xf[((wv + 8) * 64 + lane) * 8]) = v1_;          \
  } while (0)

// one full gemm+sigmoid pass: breg load + 4 tiles -> pr[64][384] in LDS
#define GEMM_PASS()                                                             \
  do {                                                                          \
    bf16x8 breg[3][16];                                                         \
    _Pragma("unroll")                                                           \
    for (int f = 0; f < 3; ++f)                                                 \
      _Pragma("unroll")                                                         \
      for (int ks = 0; ks < 16; ++ks)                                           \
        breg[f][ks] = *reinterpret_cast<const bf16x8*>(                         \
            pkc + ((size_t)(((wv * 3 + f) * 16 + ks) * 64) + lane) * 8);        \
    float4 st[4];                                                               \
    ISSUE_LOADS(0);                                                             \
    _Pragma("unroll")                                                           \
    for (int t = 0; t < 4; ++t) {                                               \
      WRITE_LDS();                                                              \
      if (t < 3) ISSUE_LOADS(t + 1);                                            \
      asm volatile("s_waitcnt lgkmcnt(0)" ::: "memory");                        \
      __builtin_amdgcn_s_barrier();                                             \
      f32x4 acc[3];                                                             \
      _Pragma("unroll")                                                         \
      for (int f = 0; f < 3; ++f) acc[f] = (f32x4){0.f, 0.f, 0.f, 0.f};         \
      _Pragma("unroll")                                                         \
      for (int ks = 0; ks < 16; ++ks) {                                         \
        bf16x8 a = *reinterpret_cast<const bf16x8*>(&xf[(ks * 64 + lane) * 8]); \
        acc[0] = __builtin_amdgcn_mfma_f32_16x16x32_bf16(a, breg[0][ks], acc[0], 0, 0, 0); \
        acc[1] = __builtin_amdgcn_mfma_f32_16x16x32_bf16(a, breg[1][ks], acc[1], 0, 0, 0); \
        acc[2] = __builtin_amdgcn_mfma_f32_16x16x32_bf16(a, breg[2][ks], acc[2], 0, 0, 0); \
      }                                                                         \
      _Pragma("unroll")                                                         \
      for (int f = 0; f < 3; ++f) {                                             \
        const int col = wv * 48 + f * 16 + (lane & 15);                         \
        _Pragma("unroll")                                                       \
        for (int r = 0; r < 4; ++r) {                                           \
          const int row = t * 16 + (lane >> 4) * 4 + r;                         \
          float z = acc[f][r] - th[f];                                          \
          float p = 1.0f / (1.0f + __expf(-z));                                 \
          pr[row * NCOL + col] = (bf16_t)p;                                     \
        }                                                                       \
      }                                                                         \
      asm volatile("s_waitcnt lgkmcnt(0)" ::: "memory");                        \
      __builtin_amdgcn_s_barrier();                                             \
    }                                                                           \
  } while (0)

// B: gemm phase only, x REPS. pr kept live via checksum to ws.
__global__ __launch_bounds__(512, 2) void node_diag_gemm(
    const float*  __restrict__ x,
    const bf16_t* __restrict__ pk,
    const float*  __restrict__ thr,
    float*        __restrict__ csum_out)
{
  DIAG_PROLOGUE();
  float csum = 0.f;
  #pragma unroll 1
  for (int rep = 0; rep < REPS; ++rep) {
    GEMM_PASS();
    csum += (float)pr[tid * 48 + rep];     // keep every rep's pr live
    __builtin_amdgcn_s_barrier();          // csum reads done before next rep
  }
  csum_out[(size_t)blockIdx.x * 512 + tid] = csum;
}

// A: full pipeline (gemm + fold + out) x REPS. out idempotent across reps.
__global__ __launch_bounds__(512, 2) void node_diag_full(
    const float*  __restrict__ x,
    const bf16_t* __restrict__ pk,
    const float*  __restrict__ thr,
    const float*  __restrict__ lw,
    float*        __restrict__ out)
{
  DIAG_PROLOGUE();
  #pragma unroll 1
  for (int rep = 0; rep < REPS; ++rep) {
    GEMM_PASS();

    // fold: lane = tree; wave wv folds rows wv*8 .. wv*8+7 (breg dead here)
    float w[64];
    #pragma unroll
    for (int j = 0; j < 16; ++j) {
      float4 f = *reinterpret_cast<const float4*>(lw + (size_t)lane * 64 + j * 4);
      w[4*j] = f.x; w[4*j+1] = f.y; w[4*j+2] = f.z; w[4*j+3] = f.w;
    }
    #pragma unroll
    for (int rr = 0; rr < 8; ++rr) {
      const int row = wv * 8 + rr;
      const unsigned int* prow =
          reinterpret_cast<const unsigned int*>(pr + row * NCOL) + lane * 3;
      unsigned int d0 = prow[0], d1 = prow[1], d2 = prow[2];
      float p[NDEPTH];
      p[0] = b2f(d0 & 0xffffu); p[1] = b2f(d0 >> 16);
      p[2] = b2f(d1 & 0xffffu); p[3] = b2f(d1 >> 16);
      p[4] = b2f(d2 & 0xffffu); p[5] = b2f(d2 >> 16);

      float v[32];
      #pragma unroll
      for (int j = 0; j < 32; ++j) v[j] = fmaf(p[5], w[2*j] - w[2*j+1], w[2*j+1]);
      #pragma unroll
      for (int j = 0; j < 16; ++j) v[j] = fmaf(p[4], v[2*j] - v[2*j+1], v[2*j+1]);
      #pragma unroll
      for (int j = 0; j < 8;  ++j) v[j] = fmaf(p[3], v[2*j] - v[2*j+1], v[2*j+1]);
      #pragma unroll
      for (int j = 0; j < 4;  ++j) v[j] = fmaf(p[2], v[2*j] - v[2*j+1], v[2*j+1]);
      #pragma unroll
      for (int j = 0; j < 2;  ++j) v[j] = fmaf(p[1], v[2*j] - v[2*j+1], v[2*j+1]);
      float tv = fmaf(p[0], v[0] - v[1], v[1]);

      #pragma unroll
      for (int off = 32; off; off >>= 1) tv += __shfl_xor(tv, off, 64);
      if (lane == 0) out[rowblk + row] = tv;
    }
    __builtin_amdgcn_s_barrier();          // fold reads done before next rep
  }
}

extern "C" void kernel_launch(void* const* d_in, const int* in_sizes, int n_in,
                              void* d_out, int out_size, void* d_ws, size_t ws_size,
                              hipStream_t stream) {
  const float* x    = (const float*)d_in[0];
  const float* fsel = (const float*)d_in[1];
  const float* thr  = (const float*)d_in[2];
  const float* lw   = (const float*)d_in[3];
  float* out = (float*)d_out;

  char* ws = (char*)d_ws;
  bf16_t* pk   = (bf16_t*)ws;                       // 8 x 393216 B
  float*  csum = (float*)(ws + 8 * 393216);         // 512 KB diag sink

  const int B = in_sizes[0] / DD;                   // 16384

  node_pack<<<dim3(96), dim3(256), 0, stream>>>(fsel, pk);
  node_diag_gemm<<<dim3(B / 64), dim3(512), 0, stream>>>(x, pk, thr, csum);
  node_diag_full<<<dim3(B / 64), dim3(512), 0, stream>>>(x, pk, thr, lw, out);
}

// Round 7
// 39.358 us; speedup vs baseline: 12.0796x; 12.0796x over previous
//
#include <hip/hip_runtime.h>

// NODE ensemble forward, round 6 — fused kernel with pinned register budget.
// R5 diagnostics: gemm phase ~6.9us (near HBM floor), fold phase ~15.7us
// caused by compiler choosing VGPR=128 (breg re-fetched from L2 every tile;
// fold spilled w[64]/v[32] to scratch: 44.5MB WRITE_SIZE).
// Fixes: amdgpu_waves_per_eu(2,2) -> 256-VGPR budget (grid is 1 block/CU so
// 128 regs bought nothing); opaque asm identity pins breg residency;
// fold row-loop unroll 2 + batched shuffle reduce; pr stride 392 (2-way free).
//
// B=16384, D=512, T=64, DEPTH=6, NCOL=384.

#define DD     512
#define NCOL   384
#define NDEPTH 6
#define PKELT  (NCOL * DD)     // elements per pk copy (196608)
#define PRSTR  392             // pr row stride in bf16 (row-pairs 16 banks apart)

typedef __bf16 bf16_t;
typedef __bf16 bf16x8 __attribute__((ext_vector_type(8)));
typedef float  f32x4  __attribute__((ext_vector_type(4)));

static __device__ __forceinline__ float b2f(unsigned int u16) {
  unsigned int t = u16 << 16;
  float f;
  __builtin_memcpy(&f, &t, 4);
  return f;
}

// pk[c][((cf*16 + ksg)*64 + lane)*8 + j] = fsel[cf*16+(lane&15)][ksg*32+(lane>>4)*8+j]
// replicated x8 (one copy per XCD's L2)
__global__ __launch_bounds__(256) void node_pack(const float* __restrict__ fsel,
                                                 bf16_t* __restrict__ pk)
{
  int tid  = blockIdx.x * 256 + threadIdx.x;   // 0..24575
  int lane = tid & 63;
  int ksg  = (tid >> 6) & 15;
  int cf   = tid >> 10;                        // 0..23
  int col  = cf * 16 + (lane & 15);
  int k    = ksg * 32 + (lane >> 4) * 8;
  float4 f0 = *reinterpret_cast<const float4*>(fsel + (size_t)col * DD + k);
  float4 f1 = *reinterpret_cast<const float4*>(fsel + (size_t)col * DD + k + 4);
  bf16x8 v;
  v[0] = (bf16_t)f0.x; v[1] = (bf16_t)f0.y; v[2] = (bf16_t)f0.z; v[3] = (bf16_t)f0.w;
  v[4] = (bf16_t)f1.x; v[5] = (bf16_t)f1.y; v[6] = (bf16_t)f1.z; v[7] = (bf16_t)f1.w;
  #pragma unroll
  for (int c = 0; c < 8; ++c)
    *reinterpret_cast<bf16x8*>(pk + (size_t)c * PKELT + (size_t)tid * 8) = v;
}

__global__ void __launch_bounds__(512) __attribute__((amdgpu_waves_per_eu(2, 2)))
node_fused(const float*  __restrict__ x,      // [B][512]
           const bf16_t* __restrict__ pk,     // packed B frags, x8 copies
           const float*  __restrict__ thr,    // [384]
           const float*  __restrict__ lw,     // [64][64]
           float*        __restrict__ out)    // [B]
{
  extern __shared__ char smem[];
  bf16_t* xf = (bf16_t*)smem;             // [8192]: x tile, MFMA frag layout (16 KiB)
  bf16_t* pr = (bf16_t*)(smem + 16384);   // [64][PRSTR]: sigmoid probs (50176 B)

  const int tid  = threadIdx.x;
  const int lane = tid & 63;
  const int wv   = tid >> 6;              // 0..7; wave owns cols wv*48..+47
  const int rowblk = blockIdx.x * 64;
  const int srow = lane & 15;
  const int skg  = lane >> 4;
  const bf16_t* pkc = pk + (size_t)(blockIdx.x & 7) * PKELT;

  // ---- B into registers, pinned resident via opaque identity ----
  bf16x8 breg[3][16];
  #pragma unroll
  for (int f = 0; f < 3; ++f) {
    #pragma unroll
    for (int ks = 0; ks < 16; ++ks) {
      breg[f][ks] = *reinterpret_cast<const bf16x8*>(
          pkc + ((size_t)(((wv * 3 + f) * 16 + ks) * 64) + lane) * 8);
      asm volatile("" : "+v"(breg[f][ks]));   // not rematerializable
    }
  }

  float th[3];
  #pragma unroll
  for (int f = 0; f < 3; ++f) th[f] = thr[wv * 48 + f * 16 + (lane & 15)];

  float4 st[4];

  #define ISSUE_LOADS(t)                                                        \
    do {                                                                        \
      const float* base_ = x + (size_t)(rowblk + (t) * 16 + srow) * DD + skg*8; \
      st[0] = *reinterpret_cast<const float4*>(base_ + wv * 32);                \
      st[1] = *reinterpret_cast<const float4*>(base_ + wv * 32 + 4);            \
      st[2] = *reinterpret_cast<const float4*>(base_ + (wv + 8) * 32);          \
      st[3] = *reinterpret_cast<const float4*>(base_ + (wv + 8) * 32 + 4);      \
    } while (0)

  #define WRITE_LDS()                                                           \
    do {                                                                        \
      bf16x8 v0_, v1_;                                                          \
      v0_[0]=(bf16_t)st[0].x; v0_[1]=(bf16_t)st[0].y;                           \
      v0_[2]=(bf16_t)st[0].z; v0_[3]=(bf16_t)st[0].w;                           \
      v0_[4]=(bf16_t)st[1].x; v0_[5]=(bf16_t)st[1].y;                           \
      v0_[6]=(bf16_t)st[1].z; v0_[7]=(bf16_t)st[1].w;                           \
      v1_[0]=(bf16_t)st[2].x; v1_[1]=(bf16_t)st[2].y;                           \
      v1_[2]=(bf16_t)st[2].z; v1_[3]=(bf16_t)st[2].w;                           \
      v1_[4]=(bf16_t)st[3].x; v1_[5]=(bf16_t)st[3].y;                           \
      v1_[6]=(bf16_t)st[3].z; v1_[7]=(bf16_t)st[3].w;                           \
      *reinterpret_cast<bf16x8*>(&xf[(wv * 64 + lane) * 8])       = v0_;        \
      *reinterpret_cast<bf16x8*>(&xf[((wv + 8) * 64 + lane) * 8]) = v1_;        \
    } while (0)

  ISSUE_LOADS(0);

  // ---- 4 tiles of 16 rows: MFMA + sigmoid -> pr (LDS) ----
  #pragma unroll
  for (int t = 0; t < 4; ++t) {
    WRITE_LDS();                       // vmcnt wait via st reg deps
    if (t < 3) ISSUE_LOADS(t + 1);     // next tile's loads fly during MFMA
    asm volatile("s_waitcnt lgkmcnt(0)" ::: "memory");
    __builtin_amdgcn_s_barrier();      // xf ready for all waves

    f32x4 acc[3];
    #pragma unroll
    for (int f = 0; f < 3; ++f) acc[f] = (f32x4){0.f, 0.f, 0.f, 0.f};

    #pragma unroll
    for (int ks = 0; ks < 16; ++ks) {
      bf16x8 a = *reinterpret_cast<const bf16x8*>(&xf[(ks * 64 + lane) * 8]);
      acc[0] = __builtin_amdgcn_mfma_f32_16x16x32_bf16(a, breg[0][ks], acc[0], 0, 0, 0);
      acc[1] = __builtin_amdgcn_mfma_f32_16x16x32_bf16(a, breg[1][ks], acc[1], 0, 0, 0);
      acc[2] = __builtin_amdgcn_mfma_f32_16x16x32_bf16(a, breg[2][ks], acc[2], 0, 0, 0);
    }

    // sigmoid + store to pr. D layout: row=(lane>>4)*4+r, col=wv*48+f*16+(lane&15)
    #pragma unroll
    for (int f = 0; f < 3; ++f) {
      const int col = wv * 48 + f * 16 + (lane & 15);
      #pragma unroll
      for (int r = 0; r < 4; ++r) {
        const int row = t * 16 + (lane >> 4) * 4 + r;
        float z = acc[f][r] - th[f];
        float p = 1.0f / (1.0f + __expf(-z));
        pr[row * PRSTR + col] = (bf16_t)p;
      }
    }

    asm volatile("s_waitcnt lgkmcnt(0)" ::: "memory");
    __builtin_amdgcn_s_barrier();      // xf reads + pr writes done
  }
  #undef ISSUE_LOADS
  #undef WRITE_LDS

  // ---- fold: lane = tree; wave wv folds rows wv*8 .. wv*8+7 (breg dead) ----
  float w[64];
  #pragma unroll
  for (int j = 0; j < 16; ++j) {
    float4 f = *reinterpret_cast<const float4*>(lw + (size_t)lane * 64 + j * 4);
    w[4*j] = f.x; w[4*j+1] = f.y; w[4*j+2] = f.z; w[4*j+3] = f.w;
  }

  float tvv[8];
  #pragma unroll 2
  for (int rr = 0; rr < 8; ++rr) {
    const int row = wv * 8 + rr;
    const unsigned int* prow =
        reinterpret_cast<const unsigned int*>(pr + row * PRSTR) + lane * 3;
    unsigned int d0 = prow[0], d1 = prow[1], d2 = prow[2];
    float p[NDEPTH];
    p[0] = b2f(d0 & 0xffffu); p[1] = b2f(d0 >> 16);
    p[2] = b2f(d1 & 0xffffu); p[3] = b2f(d1 >> 16);
    p[4] = b2f(d2 & 0xffffu); p[5] = b2f(d2 >> 16);

    float v[32];
    #pragma unroll
    for (int j = 0; j < 32; ++j) v[j] = fmaf(p[5], w[2*j] - w[2*j+1], w[2*j+1]);
    #pragma unroll
    for (int j = 0; j < 16; ++j) v[j] = fmaf(p[4], v[2*j] - v[2*j+1], v[2*j+1]);
    #pragma unroll
    for (int j = 0; j < 8;  ++j) v[j] = fmaf(p[3], v[2*j] - v[2*j+1], v[2*j+1]);
    #pragma unroll
    for (int j = 0; j < 4;  ++j) v[j] = fmaf(p[2], v[2*j] - v[2*j+1], v[2*j+1]);
    #pragma unroll
    for (int j = 0; j < 2;  ++j) v[j] = fmaf(p[1], v[2*j] - v[2*j+1], v[2*j+1]);
    tvv[rr] = fmaf(p[0], v[0] - v[1], v[1]);
  }

  // batched butterfly reduce over 64 trees: 8 independent chains
  #pragma unroll
  for (int off = 32; off; off >>= 1) {
    #pragma unroll
    for (int rr = 0; rr < 8; ++rr) tvv[rr] += __shfl_xor(tvv[rr], off, 64);
  }
  if (lane == 0) {
    #pragma unroll
    for (int rr = 0; rr < 8; ++rr) out[rowblk + wv * 8 + rr] = tvv[rr];
  }
}

extern "C" void kernel_launch(void* const* d_in, const int* in_sizes, int n_in,
                              void* d_out, int out_size, void* d_ws, size_t ws_size,
                              hipStream_t stream) {
  const float* x    = (const float*)d_in[0];
  const float* fsel = (const float*)d_in[1];
  const float* thr  = (const float*)d_in[2];
  const float* lw   = (const float*)d_in[3];
  float* out = (float*)d_out;

  bf16_t* pk = (bf16_t*)d_ws;                 // 8 x 393216 B

  const int B = in_sizes[0] / DD;             // 16384
  const int lds = 16384 + 64 * PRSTR * 2;     // 66560 B

  node_pack<<<dim3(96), dim3(256), 0, stream>>>(fsel, pk);
  node_fused<<<dim3(B / 64), dim3(512), lds, stream>>>(x, pk, thr, lw, out);
}

// Round 8
// 27.594 us; speedup vs baseline: 17.2293x; 1.4263x over previous
//
#include <hip/hip_runtime.h>

// NODE ensemble forward, round 7 — every phase fits the 128-VGPR budget.
// R5 evidence: at VGPR=128 the gemm phase ran 6.9us (~HBM floor) but the fold
// spilled w[64]+v[32] (44.5MB scratch writes, 15.7us). R6's attribute/pin fix
// regressed. This round restructures instead of fighting the allocator:
//   - fold = two 32-leaf half-trees (peak live ~85 regs, no spill)
//   - gemm = full x-block staged once in LDS (117KB total, 1 block/CU),
//     B in 8 chunks of bh[3][2] (24 regs), acc[4][3] (48 regs)
//   - s0/s1 issued up front; bh loads issued after s1 so FIFO vmcnt waits
//     never expose s1's HBM latency
//
// B=16384, D=512, T=64, DEPTH=6, NCOL=384.

#define DD     512
#define NCOL   384
#define NDEPTH 6
#define PKELT  (NCOL * DD)     // elements per pk copy (196608)
#define XSTR   522             // xs row stride (bf16): 261 dwords, odd -> 2-way free
#define PRSTR  392             // pr row stride (bf16)

typedef __bf16 bf16_t;
typedef __bf16 bf16x8 __attribute__((ext_vector_type(8)));
typedef __bf16 bf16x4 __attribute__((ext_vector_type(4)));
typedef float  f32x4  __attribute__((ext_vector_type(4)));

static __device__ __forceinline__ float b2f(unsigned int u16) {
  unsigned int t = u16 << 16;
  float f;
  __builtin_memcpy(&f, &t, 4);
  return f;
}

// pk[c][((cf*16 + ksg)*64 + lane)*8 + j] = fsel[cf*16+(lane&15)][ksg*32+(lane>>4)*8+j]
// replicated x8 (one copy per XCD's L2)
__global__ __launch_bounds__(256) void node_pack(const float* __restrict__ fsel,
                                                 bf16_t* __restrict__ pk)
{
  int tid  = blockIdx.x * 256 + threadIdx.x;   // 0..24575
  int lane = tid & 63;
  int ksg  = (tid >> 6) & 15;
  int cf   = tid >> 10;                        // 0..23
  int col  = cf * 16 + (lane & 15);
  int k    = ksg * 32 + (lane >> 4) * 8;
  float4 f0 = *reinterpret_cast<const float4*>(fsel + (size_t)col * DD + k);
  float4 f1 = *reinterpret_cast<const float4*>(fsel + (size_t)col * DD + k + 4);
  bf16x8 v;
  v[0] = (bf16_t)f0.x; v[1] = (bf16_t)f0.y; v[2] = (bf16_t)f0.z; v[3] = (bf16_t)f0.w;
  v[4] = (bf16_t)f1.x; v[5] = (bf16_t)f1.y; v[6] = (bf16_t)f1.z; v[7] = (bf16_t)f1.w;
  #pragma unroll
  for (int c = 0; c < 8; ++c)
    *reinterpret_cast<bf16x8*>(pk + (size_t)c * PKELT + (size_t)tid * 8) = v;
}

__global__ __launch_bounds__(512) void node_fused(
    const float*  __restrict__ x,      // [B][512]
    const bf16_t* __restrict__ pk,     // packed B frags, x8 copies
    const float*  __restrict__ thr,    // [384]
    const float*  __restrict__ lw,     // [64][64]
    float*        __restrict__ out)    // [B]
{
  __shared__ bf16_t xs[64 * XSTR];     // 66816 B: full x block, bf16
  __shared__ bf16_t pr[64 * PRSTR];    // 50176 B: sigmoid probs

  const int tid  = threadIdx.x;
  const int lane = tid & 63;
  const int wv   = tid >> 6;           // 0..7; wave owns cols wv*48..+47
  const int rowblk = blockIdx.x * 64;
  const int c   = lane & 15;
  const int kg  = lane >> 4;
  const bf16_t* pkc = pk + (size_t)(blockIdx.x & 7) * PKELT;

  // ---- issue both x half-loads up front (s1 flies during s0-write stall) ----
  float4 s0[8], s1[8];
  #pragma unroll
  for (int i = 0; i < 8; ++i) {
    int idx = i * 512 + tid, e = idx << 2, r = e >> 8, k = e & 255;
    s0[i] = *reinterpret_cast<const float4*>(x + (size_t)(rowblk + r) * DD + k);
  }
  #pragma unroll
  for (int i = 0; i < 8; ++i) {
    int idx = i * 512 + tid, e = idx << 2, r = e >> 8, k = e & 255;
    s1[i] = *reinterpret_cast<const float4*>(x + (size_t)(rowblk + r) * DD + 256 + k);
  }
  // write half 0 (waits s0 only; s1 stays in flight)
  #pragma unroll
  for (int i = 0; i < 8; ++i) {
    int idx = i * 512 + tid, e = idx << 2, r = e >> 8, k = e & 255;
    bf16x4 v;
    v[0] = (bf16_t)s0[i].x; v[1] = (bf16_t)s0[i].y;
    v[2] = (bf16_t)s0[i].z; v[3] = (bf16_t)s0[i].w;
    *reinterpret_cast<bf16x4*>(&xs[r * XSTR + k]) = v;
  }
  asm volatile("s_waitcnt lgkmcnt(0)" ::: "memory");
  __builtin_amdgcn_s_barrier();        // xs half-0 ready

  float th[3];
  #pragma unroll
  for (int f = 0; f < 3; ++f) th[f] = thr[wv * 48 + f * 16 + c];

  f32x4 acc[4][3];
  #pragma unroll
  for (int t = 0; t < 4; ++t)
    #pragma unroll
    for (int f = 0; f < 3; ++f) acc[t][f] = (f32x4){0.f, 0.f, 0.f, 0.f};

  // ---- GEMM: 8 K-chunks of 64; chunks 0-3 = half 0, 4-7 = half 1 ----
  #pragma unroll
  for (int ch = 0; ch < 8; ++ch) {
    if (ch == 4) {
      // write half 1 (s1 long since arrived), then make it visible
      #pragma unroll
      for (int i = 0; i < 8; ++i) {
        int idx = i * 512 + tid, e = idx << 2, r = e >> 8, k = e & 255;
        bf16x4 v;
        v[0] = (bf16_t)s1[i].x; v[1] = (bf16_t)s1[i].y;
        v[2] = (bf16_t)s1[i].z; v[3] = (bf16_t)s1[i].w;
        *reinterpret_cast<bf16x4*>(&xs[r * XSTR + 256 + k]) = v;
      }
      asm volatile("s_waitcnt lgkmcnt(0)" ::: "memory");
      __builtin_amdgcn_s_barrier();    // xs half-1 ready
    }

    bf16x8 bh[3][2];
    #pragma unroll
    for (int f = 0; f < 3; ++f)
      #pragma unroll
      for (int ks = 0; ks < 2; ++ks)
        bh[f][ks] = *reinterpret_cast<const bf16x8*>(
            pkc + ((size_t)(((wv * 3 + f) * 16 + ch * 2 + ks) * 64) + lane) * 8);

    #pragma unroll
    for (int t = 0; t < 4; ++t) {
      #pragma unroll
      for (int ks = 0; ks < 2; ++ks) {
        bf16x8 a = *reinterpret_cast<const bf16x8*>(
            &xs[(t * 16 + c) * XSTR + ch * 64 + ks * 32 + kg * 8]);
        acc[t][0] = __builtin_amdgcn_mfma_f32_16x16x32_bf16(a, bh[0][ks], acc[t][0], 0, 0, 0);
        acc[t][1] = __builtin_amdgcn_mfma_f32_16x16x32_bf16(a, bh[1][ks], acc[t][1], 0, 0, 0);
        acc[t][2] = __builtin_amdgcn_mfma_f32_16x16x32_bf16(a, bh[2][ks], acc[t][2], 0, 0, 0);
      }
    }
  }

  // ---- epilogue: sigmoid -> pr. D: row = t*16 + kg*4 + r, col = wv*48+f*16+c ----
  #pragma unroll
  for (int t = 0; t < 4; ++t) {
    #pragma unroll
    for (int f = 0; f < 3; ++f) {
      const int col = wv * 48 + f * 16 + c;
      #pragma unroll
      for (int r = 0; r < 4; ++r) {
        const int row = t * 16 + kg * 4 + r;
        float z = acc[t][f][r] - th[f];
        float p = 1.0f / (1.0f + __expf(-z));
        pr[row * PRSTR + col] = (bf16_t)p;
      }
    }
  }
  asm volatile("s_waitcnt lgkmcnt(0)" ::: "memory");
  __builtin_amdgcn_s_barrier();        // pr complete

  // ---- fold: lane = tree; two 32-leaf half-trees (peak live ~85 regs) ----
  float p0v[8], hv0[8], hv1[8];
  #pragma unroll
  for (int half = 0; half < 2; ++half) {
    float wch[32];
    #pragma unroll
    for (int j = 0; j < 8; ++j) {
      float4 f4 = *reinterpret_cast<const float4*>(lw + (size_t)lane * 64 + half * 32 + j * 4);
      wch[4*j] = f4.x; wch[4*j+1] = f4.y; wch[4*j+2] = f4.z; wch[4*j+3] = f4.w;
    }
    #pragma unroll
    for (int rr = 0; rr < 8; ++rr) {
      const int row = wv * 8 + rr;
      const unsigned int* prow =
          reinterpret_cast<const unsigned int*>(&pr[row * PRSTR]) + lane * 3;
      unsigned int d0 = prow[0], d1 = prow[1], d2 = prow[2];
      float p1 = b2f(d0 >> 16);
      float p2 = b2f(d1 & 0xffffu), p3 = b2f(d1 >> 16);
      float p4 = b2f(d2 & 0xffffu), p5 = b2f(d2 >> 16);
      if (half == 0) p0v[rr] = b2f(d0 & 0xffffu);

      float v[16];
      #pragma unroll
      for (int j = 0; j < 16; ++j) v[j] = fmaf(p5, wch[2*j] - wch[2*j+1], wch[2*j+1]);
      #pragma unroll
      for (int j = 0; j < 8;  ++j) v[j] = fmaf(p4, v[2*j] - v[2*j+1], v[2*j+1]);
      #pragma unroll
      for (int j = 0; j < 4;  ++j) v[j] = fmaf(p3, v[2*j] - v[2*j+1], v[2*j+1]);
      #pragma unroll
      for (int j = 0; j < 2;  ++j) v[j] = fmaf(p2, v[2*j] - v[2*j+1], v[2*j+1]);
      float s = fmaf(p1, v[0] - v[1], v[1]);
      if (half == 0) hv0[rr] = s; else hv1[rr] = s;
    }
  }

  float tvv[8];
  #pragma unroll
  for (int rr = 0; rr < 8; ++rr)
    tvv[rr] = fmaf(p0v[rr], hv0[rr] - hv1[rr], hv1[rr]);

  // batched butterfly over 64 trees: 8 independent chains
  #pragma unroll
  for (int off = 32; off; off >>= 1) {
    #pragma unroll
    for (int rr = 0; rr < 8; ++rr) tvv[rr] += __shfl_xor(tvv[rr], off, 64);
  }
  if (lane == 0) {
    #pragma unroll
    for (int rr = 0; rr < 8; ++rr) out[rowblk + wv * 8 + rr] = tvv[rr];
  }
}

extern "C" void kernel_launch(void* const* d_in, const int* in_sizes, int n_in,
                              void* d_out, int out_size, void* d_ws, size_t ws_size,
                              hipStream_t stream) {
  const float* x    = (const float*)d_in[0];
  const float* fsel = (const float*)d_in[1];
  const float* thr  = (const float*)d_in[2];
  const float* lw   = (const float*)d_in[3];
  float* out = (float*)d_out;

  bf16_t* pk = (bf16_t*)d_ws;                 // 8 x 393216 B

  const int B = in_sizes[0] / DD;             // 16384

  node_pack<<<dim3(96), dim3(256), 0, stream>>>(fsel, pk);
  node_fused<<<dim3(B / 64), dim3(512), 0, stream>>>(x, pk, thr, lw, out);
}